// Round 7
// baseline (372.289 us; speedup 1.0000x reference)
//
#include <hip/hip_runtime.h>
#include <hip/hip_fp16.h>

#define T_TOK 1024
#define H_DIM 2048
#define I_DIM 1408
#define N_EXP 8
#define TOPK  2

using f16x8 = __attribute__((ext_vector_type(8))) _Float16;
using f32x4 = __attribute__((ext_vector_type(4))) float;

#define BM 128
#define BN 64
#define BK 64
#define NTHR 512
#define MBLKS 16   // per-expert m-block capacity: 16*128 = 2048 slots (worst case)

// ---------------- workspace layout (bytes) ----------------
#define WS_COUNTS      0
#define WS_BASES       256
#define WS_CURSORS     512
#define WS_TOPK_E      768                       // int[2048]
#define WS_TOPK_W      (768 + 8192)              // float[2048]
#define WS_TOK_OF_SLOT 17408                     // int[3072] (padded slots <= 3064)
#define WS_W_OF_SLOT   29696                     // float[3072]
#define WS_HACT        43008                     // f16[3072*1408] = 8650752 B
#define WS_NEEDED      (43008 + 8650752)

// ---------------- router ----------------
__global__ void k_router(const float* __restrict__ X, const float* __restrict__ GW,
                         int* __restrict__ counts, int* __restrict__ topk_e,
                         float* __restrict__ topk_w) {
    int t = (blockIdx.x * blockDim.x + threadIdx.x) >> 6;
    int lane = threadIdx.x & 63;
    if (t >= T_TOK) return;
    float acc[N_EXP];
#pragma unroll
    for (int e = 0; e < N_EXP; ++e) acc[e] = 0.f;
    const float* xrow = X + (size_t)t * H_DIM;
    for (int h = lane; h < H_DIM; h += 64) {
        float x = xrow[h];
        const float* g = GW + (size_t)h * N_EXP;
#pragma unroll
        for (int e = 0; e < N_EXP; ++e) acc[e] = fmaf(x, g[e], acc[e]);
    }
#pragma unroll
    for (int off = 32; off > 0; off >>= 1) {
#pragma unroll
        for (int e = 0; e < N_EXP; ++e) acc[e] += __shfl_xor(acc[e], off, 64);
    }
    if (lane == 0) {
        float m = acc[0];
#pragma unroll
        for (int e = 1; e < N_EXP; ++e) m = fmaxf(m, acc[e]);
        float ex[N_EXP], s = 0.f;
#pragma unroll
        for (int e = 0; e < N_EXP; ++e) { ex[e] = expf(acc[e] - m); s += ex[e]; }
        float inv = 1.f / s;
        int e1 = 0;
#pragma unroll
        for (int e = 1; e < N_EXP; ++e) if (ex[e] > ex[e1]) e1 = e;
        int e2 = (e1 == 0) ? 1 : 0;
#pragma unroll
        for (int e = 0; e < N_EXP; ++e) if (e != e1 && ex[e] > ex[e2]) e2 = e;
        topk_e[t * 2 + 0] = e1;
        topk_e[t * 2 + 1] = e2;
        topk_w[t * 2 + 0] = ex[e1] * inv;
        topk_w[t * 2 + 1] = ex[e2] * inv;
        atomicAdd(&counts[e1], 1);
        atomicAdd(&counts[e2], 1);
    }
}

// bases padded to BM so every M-block belongs to exactly one expert
__global__ void k_prefix(const int* __restrict__ counts, int* __restrict__ bases,
                         int* __restrict__ cursors) {
    if (threadIdx.x == 0) {
        int b = 0;
        for (int e = 0; e < N_EXP; ++e) {
            bases[e] = b;
            b += ((counts[e] + BM - 1) / BM) * BM;
            cursors[e] = 0;
        }
    }
}

__global__ void k_scatter(const int* __restrict__ topk_e, const float* __restrict__ topk_w,
                          const int* __restrict__ bases, int* __restrict__ cursors,
                          int* __restrict__ tok_of_slot, float* __restrict__ w_of_slot) {
    int t = blockIdx.x * blockDim.x + threadIdx.x;
    if (t >= T_TOK) return;
    for (int j = 0; j < TOPK; ++j) {
        int e = topk_e[t * 2 + j];
        int pos = atomicAdd(&cursors[e], 1);
        int slot = bases[e] + pos;
        tok_of_slot[slot] = t;
        w_of_slot[slot] = topk_w[t * 2 + j];
    }
}

// ===== GEMM common: 128x64 tile, BK=64, 512 thr (8 waves, 4x2 of 32x32),
// LDS [row][8 slots of 16B], slot ^= (row&7) (r5-verified 0-conflict maps),
// 2-deep register prefetch (r4-measured best structure). =====

#define G_COMPUTE(buf)                                                          \
    do {                                                                        \
        _Pragma("unroll") for (int ks = 0; ks < 2; ++ks) {                      \
            f16x8 af[2], bf[2];                                                 \
            _Pragma("unroll") for (int ii = 0; ii < 2; ++ii) {                  \
                int r = wm + ii * 16 + rsel;                                    \
                af[ii] = *(const f16x8*)&As[buf][r][((kq + 4 * ks) ^ (r & 7)) * 8]; \
            }                                                                   \
            _Pragma("unroll") for (int jj = 0; jj < 2; ++jj) {                  \
                int r = wn + jj * 16 + rsel;                                    \
                bf[jj] = *(const f16x8*)&Bs[buf][r][((kq + 4 * ks) ^ (r & 7)) * 8]; \
            }                                                                   \
            _Pragma("unroll") for (int ii = 0; ii < 2; ++ii)                    \
                _Pragma("unroll") for (int jj = 0; jj < 2; ++jj)                \
                    acc[ii][jj] = __builtin_amdgcn_mfma_f32_16x16x32_f16(af[ii], bf[jj], acc[ii][jj], 0, 0, 0); \
        }                                                                       \
    } while (0)

// XCD-aware flat decode (r6-verified: FETCH 180->104MB): all MBLKS m-blocks of
// one (n,e) pair land on the same blockIdx%8 (same XCD, adjacent dispatch).
#define G_DECODE(NB)                                \
    const int bi = blockIdx.x;                      \
    const int xcd = bi & 7;                         \
    const int kk = bi >> 3;                         \
    const int mblk = kk & (MBLKS - 1);              \
    const int P = xcd + 8 * (kk >> 4);              \
    const int e = P / (NB);                         \
    const int n = P % (NB);

// ---------------- GEMM1: hact[slot, i] = silu(x[tok] . w1[e,:,i]) * w_slot ----------------
__global__ __launch_bounds__(NTHR, 6) void k_gemm1(
    const float* __restrict__ X, const float* __restrict__ W1,
    const int* __restrict__ counts, const int* __restrict__ bases,
    const int* __restrict__ tok_of_slot, const float* __restrict__ w_of_slot,
    _Float16* __restrict__ hact) {
    __shared__ _Float16 As[2][BM][BK];
    __shared__ _Float16 Bs[2][BN][BK];

    G_DECODE(I_DIM / BN)   // 22 n-blocks
    const int cnt = counts[e];
    const int m0 = mblk * BM;
    if (m0 >= cnt) return;
    const int base = bases[e];
    const int n0 = n * BN;
    const int tid = threadIdx.x;

    // A staging: thread -> (row 0..127, 16 consecutive floats). Balanced (r5-verified class).
    const int ar = tid >> 2;
    const int as0 = (tid & 3) * 2;          // first 16B logical slot
    const int r_eff = min(ar, cnt - m0 - 1);
    const float* arow = X + (size_t)tok_of_slot[base + m0 + r_eff] * H_DIM + (tid & 3) * 16;

    // B staging: thread -> (1 col, 8 k-rows = 1 slot-group). Balanced (r5-verified class).
    const int bn = tid & 63;
    const int bc = tid >> 6;                // logical slot 0..7
    const float* bcol = W1 + (size_t)e * (H_DIM * I_DIM) + (size_t)(bc * 8) * I_DIM + n0 + bn;

    const int wid = tid >> 6, lane = tid & 63;
    const int wm = (wid >> 1) * 32, wn = (wid & 1) * 32;
    const int rsel = lane & 15, kq = lane >> 4;

    f32x4 acc[2][2] = {};

    float aS0[16], aS1[16];
    float bS0[8],  bS1[8];

#define G1_LOAD(aS, bS, k0)                                        \
    do {                                                           \
        const float* ap = arow + (k0);                             \
        *(float4*)(aS + 0)  = *(const float4*)(ap);                \
        *(float4*)(aS + 4)  = *(const float4*)(ap + 4);            \
        *(float4*)(aS + 8)  = *(const float4*)(ap + 8);            \
        *(float4*)(aS + 12) = *(const float4*)(ap + 12);           \
        const float* bp = bcol + (size_t)(k0) * I_DIM;             \
        _Pragma("unroll") for (int j = 0; j < 8; ++j)              \
            bS[j] = bp[(size_t)j * I_DIM];                         \
    } while (0)

#define G1_STORE(buf, aS, bS)                                      \
    do {                                                           \
        f16x8 p0, p1;                                              \
        _Pragma("unroll") for (int c = 0; c < 8; ++c) {            \
            p0[c] = (_Float16)aS[c]; p1[c] = (_Float16)aS[c + 8];  \
        }                                                          \
        *(f16x8*)&As[buf][ar][((as0) ^ (ar & 7)) * 8] = p0;        \
        *(f16x8*)&As[buf][ar][((as0 + 1) ^ (ar & 7)) * 8] = p1;    \
        f16x8 q;                                                   \
        _Pragma("unroll") for (int j = 0; j < 8; ++j)              \
            q[j] = (_Float16)bS[j];                                \
        *(f16x8*)&Bs[buf][bn][((bc) ^ (bn & 7)) * 8] = q;          \
    } while (0)

    constexpr int KT = H_DIM / BK;   // 32, even
    G1_LOAD(aS0, bS0, 0);
    G1_STORE(0, aS0, bS0);
    G1_LOAD(aS0, bS0, BK);           // set0 holds tile 1
    __syncthreads();
    for (int kt = 0; kt < KT; kt += 2) {
        if (kt + 2 < KT) G1_LOAD(aS1, bS1, (kt + 2) * BK);
        G_COMPUTE(0);
        if (kt + 1 < KT) G1_STORE(1, aS0, bS0);
        __syncthreads();
        if (kt + 3 < KT) G1_LOAD(aS0, bS0, (kt + 3) * BK);
        if (kt + 1 < KT) {
            G_COMPUTE(1);
            if (kt + 2 < KT) G1_STORE(0, aS1, bS1);
            __syncthreads();
        }
    }
#undef G1_LOAD
#undef G1_STORE

    const int rows = cnt - m0;
#pragma unroll
    for (int i = 0; i < 2; ++i) {
#pragma unroll
        for (int rg = 0; rg < 4; ++rg) {
            int r = wm + i * 16 + kq * 4 + rg;
            if (r < rows) {
                int slot = base + m0 + r;
                float w = w_of_slot[slot];
                _Float16* hrow = hact + (size_t)slot * I_DIM + n0;
#pragma unroll
                for (int j = 0; j < 2; ++j) {
                    float v = acc[i][j][rg];
                    hrow[wn + j * 16 + rsel] = (_Float16)(v / (1.f + expf(-v)) * w);
                }
            }
        }
    }
}

// ---------------- GEMM2: out[tok, h] += hact[slot, :] . w2[e, :, h] ----------------
__global__ __launch_bounds__(NTHR, 6) void k_gemm2(
    const _Float16* __restrict__ hact, const float* __restrict__ W2,
    const int* __restrict__ counts, const int* __restrict__ bases,
    const int* __restrict__ tok_of_slot, float* __restrict__ out) {
    __shared__ _Float16 As[2][BM][BK];
    __shared__ _Float16 Bs[2][BN][BK];

    G_DECODE(H_DIM / BN)   // 32 n-blocks
    const int cnt = counts[e];
    const int m0 = mblk * BM;
    if (m0 >= cnt) return;
    const int base = bases[e];
    const int n0 = n * BN;
    const int tid = threadIdx.x;

    const int ar = tid >> 2;
    const int as0 = (tid & 3) * 2;
    const int r_eff = min(ar, cnt - m0 - 1);
    const _Float16* arow = hact + (size_t)(base + m0 + r_eff) * I_DIM + (tid & 3) * 16;

    const int bn = tid & 63;
    const int bc = tid >> 6;
    const float* bcol = W2 + (size_t)e * (I_DIM * H_DIM) + (size_t)(bc * 8) * H_DIM + n0 + bn;

    const int wid = tid >> 6, lane = tid & 63;
    const int wm = (wid >> 1) * 32, wn = (wid & 1) * 32;
    const int rsel = lane & 15, kq = lane >> 4;

    f32x4 acc[2][2] = {};

    f16x8 aS0[2], aS1[2];
    float bS0[8], bS1[8];

#define G2_LOAD(aS, bS, k0)                                        \
    do {                                                           \
        const _Float16* ap = arow + (k0);                          \
        aS[0] = *(const f16x8*)(ap);                               \
        aS[1] = *(const f16x8*)(ap + 8);                           \
        const float* bp = bcol + (size_t)(k0) * H_DIM;             \
        _Pragma("unroll") for (int j = 0; j < 8; ++j)              \
            bS[j] = bp[(size_t)j * H_DIM];                         \
    } while (0)

#define G2_STORE(buf, aS, bS)                                      \
    do {                                                           \
        *(f16x8*)&As[buf][ar][((as0) ^ (ar & 7)) * 8] = aS[0];     \
        *(f16x8*)&As[buf][ar][((as0 + 1) ^ (ar & 7)) * 8] = aS[1]; \
        f16x8 q;                                                   \
        _Pragma("unroll") for (int j = 0; j < 8; ++j)              \
            q[j] = (_Float16)bS[j];                                \
        *(f16x8*)&Bs[buf][bn][((bc) ^ (bn & 7)) * 8] = q;          \
    } while (0)

    constexpr int KT = I_DIM / BK;   // 22, even
    G2_LOAD(aS0, bS0, 0);
    G2_STORE(0, aS0, bS0);
    G2_LOAD(aS0, bS0, BK);
    __syncthreads();
    for (int kt = 0; kt < KT; kt += 2) {
        if (kt + 2 < KT) G2_LOAD(aS1, bS1, (kt + 2) * BK);
        G_COMPUTE(0);
        if (kt + 1 < KT) G2_STORE(1, aS0, bS0);
        __syncthreads();
        if (kt + 3 < KT) G2_LOAD(aS0, bS0, (kt + 3) * BK);
        if (kt + 1 < KT) {
            G_COMPUTE(1);
            if (kt + 2 < KT) G2_STORE(0, aS1, bS1);
            __syncthreads();
        }
    }
#undef G2_LOAD
#undef G2_STORE

    const int rows = cnt - m0;
#pragma unroll
    for (int i = 0; i < 2; ++i) {
#pragma unroll
        for (int rg = 0; rg < 4; ++rg) {
            int r = wm + i * 16 + kq * 4 + rg;
            if (r < rows) {
                int slot = base + m0 + r;
                int tok = tok_of_slot[slot];
                float* orow = out + (size_t)tok * H_DIM + n0;
#pragma unroll
                for (int j = 0; j < 2; ++j)
                    atomicAdd(&orow[wn + j * 16 + rsel], acc[i][j][rg]);
            }
        }
    }
}

extern "C" void kernel_launch(void* const* d_in, const int* in_sizes, int n_in,
                              void* d_out, int out_size, void* d_ws, size_t ws_size,
                              hipStream_t stream) {
    const float* X  = (const float*)d_in[0];
    const float* GW = (const float*)d_in[1];
    const float* W1 = (const float*)d_in[2];
    const float* W2 = (const float*)d_in[3];
    float* out = (float*)d_out;
    char* ws = (char*)d_ws;
    if (ws_size < (size_t)WS_NEEDED) return;

    int*   counts      = (int*)(ws + WS_COUNTS);
    int*   bases       = (int*)(ws + WS_BASES);
    int*   cursors     = (int*)(ws + WS_CURSORS);
    int*   topk_e      = (int*)(ws + WS_TOPK_E);
    float* topk_w      = (float*)(ws + WS_TOPK_W);
    int*   tok_of_slot = (int*)(ws + WS_TOK_OF_SLOT);
    float* w_of_slot   = (float*)(ws + WS_W_OF_SLOT);
    _Float16* hact     = (_Float16*)(ws + WS_HACT);

    hipMemsetAsync(counts, 0, N_EXP * sizeof(int), stream);
    k_router<<<T_TOK / 4, 256, 0, stream>>>(X, GW, counts, topk_e, topk_w);
    k_prefix<<<1, 64, 0, stream>>>(counts, bases, cursors);
    k_scatter<<<T_TOK / 256, 256, 0, stream>>>(topk_e, topk_w, bases, cursors,
                                               tok_of_slot, w_of_slot);
    hipMemsetAsync(out, 0, (size_t)T_TOK * H_DIM * sizeof(float), stream);
    // gemm1: 22 n-blocks x 8 experts, MBLKS m-blocks per pair (XCD-decoded flat grid)
    k_gemm1<<<8 * MBLKS * 22, NTHR, 0, stream>>>(
        X, W1, counts, bases, tok_of_slot, w_of_slot, hact);
    // gemm2: 32 n-blocks x 8 experts
    k_gemm2<<<8 * MBLKS * 32, NTHR, 0, stream>>>(
        hact, W2, counts, bases, tok_of_slot, out);
}

// Round 8
// 184.559 us; speedup vs baseline: 2.0172x; 2.0172x over previous
//
#include <hip/hip_runtime.h>
#include <hip/hip_fp16.h>

#define T_TOK 1024
#define H_DIM 2048
#define I_DIM 1408
#define N_EXP 8
#define TOPK  2

using f16x8 = __attribute__((ext_vector_type(8))) _Float16;
using f32x4 = __attribute__((ext_vector_type(4))) float;

#define BM 128
#define BN 64
#define BK 64
#define NTHR 512
#define MBLKS 8    // per-expert m-block capacity: 8*128 = 1024 slots (cnt_e <= 1024 exact)

// ---------------- workspace layout (bytes) ----------------
#define WS_COUNTS      0
#define WS_BASES       256
#define WS_CURSORS     512
#define WS_TOPK_E      768                       // int[2048]
#define WS_TOPK_W      (768 + 8192)              // float[2048]
#define WS_TOK_OF_SLOT 17408                     // int[3072] (padded slots <= 3064)
#define WS_W_OF_SLOT   29696                     // float[3072]
#define WS_HACT        43008                     // f16[3072*1408] = 8650752 B
#define WS_NEEDED      (43008 + 8650752)

// ---------------- router ----------------
__global__ void k_router(const float* __restrict__ X, const float* __restrict__ GW,
                         int* __restrict__ counts, int* __restrict__ topk_e,
                         float* __restrict__ topk_w) {
    int t = (blockIdx.x * blockDim.x + threadIdx.x) >> 6;
    int lane = threadIdx.x & 63;
    if (t >= T_TOK) return;
    float acc[N_EXP];
#pragma unroll
    for (int e = 0; e < N_EXP; ++e) acc[e] = 0.f;
    const float* xrow = X + (size_t)t * H_DIM;
    for (int h = lane; h < H_DIM; h += 64) {
        float x = xrow[h];
        const float* g = GW + (size_t)h * N_EXP;
#pragma unroll
        for (int e = 0; e < N_EXP; ++e) acc[e] = fmaf(x, g[e], acc[e]);
    }
#pragma unroll
    for (int off = 32; off > 0; off >>= 1) {
#pragma unroll
        for (int e = 0; e < N_EXP; ++e) acc[e] += __shfl_xor(acc[e], off, 64);
    }
    if (lane == 0) {
        float m = acc[0];
#pragma unroll
        for (int e = 1; e < N_EXP; ++e) m = fmaxf(m, acc[e]);
        float ex[N_EXP], s = 0.f;
#pragma unroll
        for (int e = 0; e < N_EXP; ++e) { ex[e] = expf(acc[e] - m); s += ex[e]; }
        float inv = 1.f / s;
        int e1 = 0;
#pragma unroll
        for (int e = 1; e < N_EXP; ++e) if (ex[e] > ex[e1]) e1 = e;
        int e2 = (e1 == 0) ? 1 : 0;
#pragma unroll
        for (int e = 0; e < N_EXP; ++e) if (e != e1 && ex[e] > ex[e2]) e2 = e;
        topk_e[t * 2 + 0] = e1;
        topk_e[t * 2 + 1] = e2;
        topk_w[t * 2 + 0] = ex[e1] * inv;
        topk_w[t * 2 + 1] = ex[e2] * inv;
        atomicAdd(&counts[e1], 1);
        atomicAdd(&counts[e2], 1);
    }
}

// bases padded to BM so every M-block belongs to exactly one expert
__global__ void k_prefix(const int* __restrict__ counts, int* __restrict__ bases,
                         int* __restrict__ cursors) {
    if (threadIdx.x == 0) {
        int b = 0;
        for (int e = 0; e < N_EXP; ++e) {
            bases[e] = b;
            b += ((counts[e] + BM - 1) / BM) * BM;
            cursors[e] = 0;
        }
    }
}

__global__ void k_scatter(const int* __restrict__ topk_e, const float* __restrict__ topk_w,
                          const int* __restrict__ bases, int* __restrict__ cursors,
                          int* __restrict__ tok_of_slot, float* __restrict__ w_of_slot) {
    int t = blockIdx.x * blockDim.x + threadIdx.x;
    if (t >= T_TOK) return;
    for (int j = 0; j < TOPK; ++j) {
        int e = topk_e[t * 2 + j];
        int pos = atomicAdd(&cursors[e], 1);
        int slot = bases[e] + pos;
        tok_of_slot[slot] = t;
        w_of_slot[slot] = topk_w[t * 2 + j];
    }
}

// ===== GEMM common (r3-measured best: 85us, VGPR 60, 0 conflicts):
// 128x64 tile, BK=64, 512 thr (8 waves, 4x2 of 32x32),
// LDS [row][8 slots of 16B], slot ^= (row&7), 2-deep register prefetch. =====

#define G_COMPUTE(buf)                                                          \
    do {                                                                        \
        _Pragma("unroll") for (int ks = 0; ks < 2; ++ks) {                      \
            f16x8 af[2], bf[2];                                                 \
            _Pragma("unroll") for (int ii = 0; ii < 2; ++ii) {                  \
                int r = wm + ii * 16 + rsel;                                    \
                af[ii] = *(const f16x8*)&As[buf][r][((kq + 4 * ks) ^ (r & 7)) * 8]; \
            }                                                                   \
            _Pragma("unroll") for (int jj = 0; jj < 2; ++jj) {                  \
                int r = wn + jj * 16 + rsel;                                    \
                bf[jj] = *(const f16x8*)&Bs[buf][r][((kq + 4 * ks) ^ (r & 7)) * 8]; \
            }                                                                   \
            _Pragma("unroll") for (int ii = 0; ii < 2; ++ii)                    \
                _Pragma("unroll") for (int jj = 0; jj < 2; ++jj)                \
                    acc[ii][jj] = __builtin_amdgcn_mfma_f32_16x16x32_f16(af[ii], bf[jj], acc[ii][jj], 0, 0, 0); \
        }                                                                       \
    } while (0)

// XCD-aware flat decode (r6-verified: FETCH 180->104MB): all MBLKS m-blocks of
// one (n,e) pair land on the same blockIdx%8 (same XCD, adjacent dispatch).
#define G_DECODE(NB)                                \
    const int bi = blockIdx.x;                      \
    const int xcd = bi & 7;                         \
    const int kk = bi >> 3;                         \
    const int mblk = kk & (MBLKS - 1);              \
    const int P = xcd + 8 * (kk / MBLKS);           \
    const int e = P / (NB);                         \
    const int n = P % (NB);

// ---------------- GEMM1: hact[slot, i] = silu(x[tok] . w1[e,:,i]) * w_slot ----------------
__global__ __launch_bounds__(NTHR, 4) void k_gemm1(
    const float* __restrict__ X, const float* __restrict__ W1,
    const int* __restrict__ counts, const int* __restrict__ bases,
    const int* __restrict__ tok_of_slot, const float* __restrict__ w_of_slot,
    _Float16* __restrict__ hact) {
    __shared__ _Float16 As[2][BM][BK];
    __shared__ _Float16 Bs[2][BN][BK];

    G_DECODE(I_DIM / BN)   // 22 n-blocks
    const int cnt = counts[e];
    const int m0 = mblk * BM;
    if (m0 >= cnt) return;
    const int base = bases[e];
    const int n0 = n * BN;
    const int tid = threadIdx.x;

    // A staging: thread -> (row 0..127, 16-float k chunk). r3-verified balanced.
    const int ar = tid >> 2;
    const int ac2 = (tid & 3) * 2;              // first 8-half slot index (0,2,4,6)
    const int r_eff = min(ar, cnt - m0 - 1);
    const float* arow = X + (size_t)tok_of_slot[base + m0 + r_eff] * H_DIM + (tid & 3) * 16;

    // B staging: thread -> (col n 0..63, 8 k-rows). r3-verified balanced.
    const int bn = tid & 63;
    const int bc = tid >> 6;                    // slot index 0..7
    const float* bcol = W1 + (size_t)e * (H_DIM * I_DIM) + (size_t)(bc * 8) * I_DIM + n0 + bn;

    const int wid = tid >> 6, lane = tid & 63;
    const int wm = (wid >> 1) * 32, wn = (wid & 1) * 32;
    const int rsel = lane & 15, kq = lane >> 4;

    f32x4 acc[2][2] = {};

    float4 aR0[4]; float bR0[8];
    float4 aR1[4]; float bR1[8];

#define LOAD1(aR, bR, k0)                                              \
    do {                                                               \
        aR[0] = *(const float4*)(arow + (k0));                         \
        aR[1] = *(const float4*)(arow + (k0) + 4);                     \
        aR[2] = *(const float4*)(arow + (k0) + 8);                     \
        aR[3] = *(const float4*)(arow + (k0) + 12);                    \
        const float* bp = bcol + (size_t)(k0) * I_DIM;                 \
        _Pragma("unroll") for (int j = 0; j < 8; ++j)                  \
            bR[j] = bp[(size_t)j * I_DIM];                             \
    } while (0)

#define STORE1(buf, aR, bR)                                            \
    do {                                                               \
        f16x8 p0, p1;                                                  \
        _Pragma("unroll") for (int j = 0; j < 4; ++j) {                \
            p0[j]     = (_Float16)aR[0][j];                            \
            p0[j + 4] = (_Float16)aR[1][j];                            \
            p1[j]     = (_Float16)aR[2][j];                            \
            p1[j + 4] = (_Float16)aR[3][j];                            \
        }                                                              \
        *(f16x8*)&As[buf][ar][((ac2) ^ (ar & 7)) * 8] = p0;            \
        *(f16x8*)&As[buf][ar][((ac2 + 1) ^ (ar & 7)) * 8] = p1;        \
        f16x8 q;                                                       \
        _Pragma("unroll") for (int j = 0; j < 8; ++j)                  \
            q[j] = (_Float16)bR[j];                                    \
        *(f16x8*)&Bs[buf][bn][(bc ^ (bn & 7)) * 8] = q;                \
    } while (0)

    const int KT = H_DIM / BK;   // 32, even
    LOAD1(aR0, bR0, 0);
    STORE1(0, aR0, bR0);
    LOAD1(aR0, bR0, BK);         // set0 now holds tile 1
    __syncthreads();
    for (int kt = 0; kt < KT; kt += 2) {
        if (kt + 2 < KT) LOAD1(aR1, bR1, (kt + 2) * BK);
        G_COMPUTE(0);
        if (kt + 1 < KT) STORE1(1, aR0, bR0);
        __syncthreads();
        if (kt + 3 < KT) LOAD1(aR0, bR0, (kt + 3) * BK);
        if (kt + 1 < KT) {
            G_COMPUTE(1);
            if (kt + 2 < KT) STORE1(0, aR1, bR1);
            __syncthreads();
        }
    }
#undef LOAD1
#undef STORE1

    const int rows = cnt - m0;
#pragma unroll
    for (int i = 0; i < 2; ++i) {
#pragma unroll
        for (int rg = 0; rg < 4; ++rg) {
            int r = wm + i * 16 + kq * 4 + rg;
            if (r < rows) {
                int slot = base + m0 + r;
                float w = w_of_slot[slot];
                _Float16* hrow = hact + (size_t)slot * I_DIM + n0;
#pragma unroll
                for (int j = 0; j < 2; ++j) {
                    float v = acc[i][j][rg];
                    hrow[wn + j * 16 + rsel] = (_Float16)(v / (1.f + expf(-v)) * w);
                }
            }
        }
    }
}

// ---------------- GEMM2: out[tok, h] += hact[slot, :] . w2[e, :, h] ----------------
__global__ __launch_bounds__(NTHR, 4) void k_gemm2(
    const _Float16* __restrict__ hact, const float* __restrict__ W2,
    const int* __restrict__ counts, const int* __restrict__ bases,
    const int* __restrict__ tok_of_slot, float* __restrict__ out) {
    __shared__ _Float16 As[2][BM][BK];
    __shared__ _Float16 Bs[2][BN][BK];

    G_DECODE(H_DIM / BN)   // 32 n-blocks
    const int cnt = counts[e];
    const int m0 = mblk * BM;
    if (m0 >= cnt) return;
    const int base = bases[e];
    const int n0 = n * BN;
    const int tid = threadIdx.x;

    const int ar = tid >> 2;
    const int ac2 = (tid & 3) * 2;
    const int r_eff = min(ar, cnt - m0 - 1);
    const _Float16* arow = hact + (size_t)(base + m0 + r_eff) * I_DIM + (tid & 3) * 16;

    const int bn = tid & 63;
    const int bc = tid >> 6;
    const float* bcol = W2 + (size_t)e * (I_DIM * H_DIM) + (size_t)(bc * 8) * H_DIM + n0 + bn;

    const int wid = tid >> 6, lane = tid & 63;
    const int wm = (wid >> 1) * 32, wn = (wid & 1) * 32;
    const int rsel = lane & 15, kq = lane >> 4;

    f32x4 acc[2][2] = {};

    f16x8 aR0[2]; float bR0[8];
    f16x8 aR1[2]; float bR1[8];

#define LOAD2(aR, bR, k0)                                              \
    do {                                                               \
        aR[0] = *(const f16x8*)(arow + (k0));                          \
        aR[1] = *(const f16x8*)(arow + (k0) + 8);                      \
        const float* bp = bcol + (size_t)(k0) * H_DIM;                 \
        _Pragma("unroll") for (int j = 0; j < 8; ++j)                  \
            bR[j] = bp[(size_t)j * H_DIM];                             \
    } while (0)

#define STORE2(buf, aR, bR)                                            \
    do {                                                               \
        *(f16x8*)&As[buf][ar][((ac2) ^ (ar & 7)) * 8] = aR[0];         \
        *(f16x8*)&As[buf][ar][((ac2 + 1) ^ (ar & 7)) * 8] = aR[1];     \
        f16x8 q;                                                       \
        _Pragma("unroll") for (int j = 0; j < 8; ++j)                  \
            q[j] = (_Float16)bR[j];                                    \
        *(f16x8*)&Bs[buf][bn][(bc ^ (bn & 7)) * 8] = q;                \
    } while (0)

    const int KT = I_DIM / BK;   // 22, even
    LOAD2(aR0, bR0, 0);
    STORE2(0, aR0, bR0);
    LOAD2(aR0, bR0, BK);
    __syncthreads();
    for (int kt = 0; kt < KT; kt += 2) {
        if (kt + 2 < KT) LOAD2(aR1, bR1, (kt + 2) * BK);
        G_COMPUTE(0);
        if (kt + 1 < KT) STORE2(1, aR0, bR0);
        __syncthreads();
        if (kt + 3 < KT) LOAD2(aR0, bR0, (kt + 3) * BK);
        if (kt + 1 < KT) {
            G_COMPUTE(1);
            if (kt + 2 < KT) STORE2(0, aR1, bR1);
            __syncthreads();
        }
    }
#undef LOAD2
#undef STORE2

    const int rows = cnt - m0;
#pragma unroll
    for (int i = 0; i < 2; ++i) {
#pragma unroll
        for (int rg = 0; rg < 4; ++rg) {
            int r = wm + i * 16 + kq * 4 + rg;
            if (r < rows) {
                int slot = base + m0 + r;
                int tok = tok_of_slot[slot];
                float* orow = out + (size_t)tok * H_DIM + n0;
#pragma unroll
                for (int j = 0; j < 2; ++j)
                    atomicAdd(&orow[wn + j * 16 + rsel], acc[i][j][rg]);
            }
        }
    }
}

extern "C" void kernel_launch(void* const* d_in, const int* in_sizes, int n_in,
                              void* d_out, int out_size, void* d_ws, size_t ws_size,
                              hipStream_t stream) {
    const float* X  = (const float*)d_in[0];
    const float* GW = (const float*)d_in[1];
    const float* W1 = (const float*)d_in[2];
    const float* W2 = (const float*)d_in[3];
    float* out = (float*)d_out;
    char* ws = (char*)d_ws;
    if (ws_size < (size_t)WS_NEEDED) return;

    int*   counts      = (int*)(ws + WS_COUNTS);
    int*   bases       = (int*)(ws + WS_BASES);
    int*   cursors     = (int*)(ws + WS_CURSORS);
    int*   topk_e      = (int*)(ws + WS_TOPK_E);
    float* topk_w      = (float*)(ws + WS_TOPK_W);
    int*   tok_of_slot = (int*)(ws + WS_TOK_OF_SLOT);
    float* w_of_slot   = (float*)(ws + WS_W_OF_SLOT);
    _Float16* hact     = (_Float16*)(ws + WS_HACT);

    hipMemsetAsync(counts, 0, N_EXP * sizeof(int), stream);
    k_router<<<T_TOK / 4, 256, 0, stream>>>(X, GW, counts, topk_e, topk_w);
    k_prefix<<<1, 64, 0, stream>>>(counts, bases, cursors);
    k_scatter<<<T_TOK / 256, 256, 0, stream>>>(topk_e, topk_w, bases, cursors,
                                               tok_of_slot, w_of_slot);
    hipMemsetAsync(out, 0, (size_t)T_TOK * H_DIM * sizeof(float), stream);
    // gemm1: 22 n-blocks x 8 experts, MBLKS m-blocks per pair (XCD-decoded flat grid)
    k_gemm1<<<8 * MBLKS * 22, NTHR, 0, stream>>>(
        X, W1, counts, bases, tok_of_slot, w_of_slot, hact);
    // gemm2: 32 n-blocks x 8 experts
    k_gemm2<<<8 * MBLKS * 32, NTHR, 0, stream>>>(
        hact, W2, counts, bases, tok_of_slot, out);
}

// Round 9
// 167.791 us; speedup vs baseline: 2.2188x; 1.0999x over previous
//
#include <hip/hip_runtime.h>
#include <hip/hip_fp16.h>

#define T_TOK 1024
#define H_DIM 2048
#define I_DIM 1408
#define N_EXP 8
#define TOPK  2

using f16x8 = __attribute__((ext_vector_type(8))) _Float16;
using f32x4 = __attribute__((ext_vector_type(4))) float;

#define BM 128
#define BN 64
#define BK 64
#define NTHR 512

// Barrier WITHOUT the vmcnt(0) drain __syncthreads() would emit: only LDS ops
// (ds_write) must complete before waves cross; in-flight global VGPR prefetch
// loads legally stay outstanding across the barrier (counted vmcnt at use).
#define BAR()                                                     \
    do {                                                          \
        asm volatile("s_waitcnt lgkmcnt(0)" ::: "memory");        \
        __builtin_amdgcn_s_barrier();                             \
    } while (0)

// ---------------- workspace layout (bytes) ----------------
#define WS_COUNTS      0
#define WS_BASES       256
#define WS_CURSORS     512
#define WS_TOPK_E      768                       // int[2048]
#define WS_TOPK_W      (768 + 8192)              // float[2048]
#define WS_TOK_OF_SLOT 17408                     // int[3072] (padded slots <= 3064)
#define WS_W_OF_SLOT   29696                     // float[3072]
#define WS_HACT        43008                     // f16[3072*1408] = 8650752 B
#define WS_NEEDED      (43008 + 8650752)

// ---------------- router ----------------
__global__ void k_router(const float* __restrict__ X, const float* __restrict__ GW,
                         int* __restrict__ counts, int* __restrict__ topk_e,
                         float* __restrict__ topk_w) {
    int t = (blockIdx.x * blockDim.x + threadIdx.x) >> 6;
    int lane = threadIdx.x & 63;
    if (t >= T_TOK) return;
    float acc[N_EXP];
#pragma unroll
    for (int e = 0; e < N_EXP; ++e) acc[e] = 0.f;
    const float* xrow = X + (size_t)t * H_DIM;
    for (int h = lane; h < H_DIM; h += 64) {
        float x = xrow[h];
        const float* g = GW + (size_t)h * N_EXP;
#pragma unroll
        for (int e = 0; e < N_EXP; ++e) acc[e] = fmaf(x, g[e], acc[e]);
    }
#pragma unroll
    for (int off = 32; off > 0; off >>= 1) {
#pragma unroll
        for (int e = 0; e < N_EXP; ++e) acc[e] += __shfl_xor(acc[e], off, 64);
    }
    if (lane == 0) {
        float m = acc[0];
#pragma unroll
        for (int e = 1; e < N_EXP; ++e) m = fmaxf(m, acc[e]);
        float ex[N_EXP], s = 0.f;
#pragma unroll
        for (int e = 0; e < N_EXP; ++e) { ex[e] = expf(acc[e] - m); s += ex[e]; }
        float inv = 1.f / s;
        int e1 = 0;
#pragma unroll
        for (int e = 1; e < N_EXP; ++e) if (ex[e] > ex[e1]) e1 = e;
        int e2 = (e1 == 0) ? 1 : 0;
#pragma unroll
        for (int e = 0; e < N_EXP; ++e) if (e != e1 && ex[e] > ex[e2]) e2 = e;
        topk_e[t * 2 + 0] = e1;
        topk_e[t * 2 + 1] = e2;
        topk_w[t * 2 + 0] = ex[e1] * inv;
        topk_w[t * 2 + 1] = ex[e2] * inv;
        atomicAdd(&counts[e1], 1);
        atomicAdd(&counts[e2], 1);
    }
}

// bases padded to BM so every M-block belongs to exactly one expert
__global__ void k_prefix(const int* __restrict__ counts, int* __restrict__ bases,
                         int* __restrict__ cursors) {
    if (threadIdx.x == 0) {
        int b = 0;
        for (int e = 0; e < N_EXP; ++e) {
            bases[e] = b;
            b += ((counts[e] + BM - 1) / BM) * BM;
            cursors[e] = 0;
        }
    }
}

__global__ void k_scatter(const int* __restrict__ topk_e, const float* __restrict__ topk_w,
                          const int* __restrict__ bases, int* __restrict__ cursors,
                          int* __restrict__ tok_of_slot, float* __restrict__ w_of_slot) {
    int t = blockIdx.x * blockDim.x + threadIdx.x;
    if (t >= T_TOK) return;
    for (int j = 0; j < TOPK; ++j) {
        int e = topk_e[t * 2 + j];
        int pos = atomicAdd(&cursors[e], 1);
        int slot = bases[e] + pos;
        tok_of_slot[slot] = t;
        w_of_slot[slot] = topk_w[t * 2 + j];
    }
}

// ===== GEMM common (r3-measured structure: VGPR 60, 0 conflicts):
// 128x64 tile, BK=64, 512 thr (8 waves, 4x2 of 32x32),
// LDS [row][8 slots of 16B], slot ^= (row&7), 2-deep register prefetch,
// drain-free barriers (loads stay in flight across BAR). =====

#define G_COMPUTE(buf)                                                          \
    do {                                                                        \
        _Pragma("unroll") for (int ks = 0; ks < 2; ++ks) {                      \
            f16x8 af[2], bf[2];                                                 \
            _Pragma("unroll") for (int ii = 0; ii < 2; ++ii) {                  \
                int r = wm + ii * 16 + rsel;                                    \
                af[ii] = *(const f16x8*)&As[buf][r][((kq + 4 * ks) ^ (r & 7)) * 8]; \
            }                                                                   \
            _Pragma("unroll") for (int jj = 0; jj < 2; ++jj) {                  \
                int r = wn + jj * 16 + rsel;                                    \
                bf[jj] = *(const f16x8*)&Bs[buf][r][((kq + 4 * ks) ^ (r & 7)) * 8]; \
            }                                                                   \
            _Pragma("unroll") for (int ii = 0; ii < 2; ++ii)                    \
                _Pragma("unroll") for (int jj = 0; jj < 2; ++jj)                \
                    acc[ii][jj] = __builtin_amdgcn_mfma_f32_16x16x32_f16(af[ii], bf[jj], acc[ii][jj], 0, 0, 0); \
        }                                                                       \
    } while (0)

// ---------------- GEMM1: hact[slot, i] = silu(x[tok] . w1[e,:,i]) * w_slot ----------------
__global__ __launch_bounds__(NTHR, 4) void k_gemm1(
    const float* __restrict__ X, const float* __restrict__ W1,
    const int* __restrict__ counts, const int* __restrict__ bases,
    const int* __restrict__ tok_of_slot, const float* __restrict__ w_of_slot,
    _Float16* __restrict__ hact) {
    __shared__ _Float16 As[2][BM][BK];
    __shared__ _Float16 Bs[2][BN][BK];

    const int e = blockIdx.z;
    const int cnt = counts[e];
    const int m0 = blockIdx.y * BM;
    if (m0 >= cnt) return;
    const int base = bases[e];
    const int n0 = blockIdx.x * BN;
    const int tid = threadIdx.x;

    // A staging: thread -> (row 0..127, 16-float k chunk). r3-verified balanced.
    const int ar = tid >> 2;
    const int ac2 = (tid & 3) * 2;              // first 8-half slot index (0,2,4,6)
    const int r_eff = min(ar, cnt - m0 - 1);
    const float* arow = X + (size_t)tok_of_slot[base + m0 + r_eff] * H_DIM + (tid & 3) * 16;

    // B staging: thread -> (col n 0..63, 8 k-rows). r3-verified balanced.
    const int bn = tid & 63;
    const int bc = tid >> 6;                    // slot index 0..7
    const float* bcol = W1 + (size_t)e * (H_DIM * I_DIM) + (size_t)(bc * 8) * I_DIM + n0 + bn;

    const int wid = tid >> 6, lane = tid & 63;
    const int wm = (wid >> 1) * 32, wn = (wid & 1) * 32;
    const int rsel = lane & 15, kq = lane >> 4;

    f32x4 acc[2][2] = {};

    float4 aR0[4]; float bR0[8];
    float4 aR1[4]; float bR1[8];

#define LOAD1(aR, bR, k0)                                              \
    do {                                                               \
        aR[0] = *(const float4*)(arow + (k0));                         \
        aR[1] = *(const float4*)(arow + (k0) + 4);                     \
        aR[2] = *(const float4*)(arow + (k0) + 8);                     \
        aR[3] = *(const float4*)(arow + (k0) + 12);                    \
        const float* bp = bcol + (size_t)(k0) * I_DIM;                 \
        _Pragma("unroll") for (int j = 0; j < 8; ++j)                  \
            bR[j] = bp[(size_t)j * I_DIM];                             \
    } while (0)

#define STORE1(buf, aR, bR)                                            \
    do {                                                               \
        f16x8 p0, p1;                                                  \
        _Pragma("unroll") for (int j = 0; j < 4; ++j) {                \
            p0[j]     = (_Float16)aR[0][j];                            \
            p0[j + 4] = (_Float16)aR[1][j];                            \
            p1[j]     = (_Float16)aR[2][j];                            \
            p1[j + 4] = (_Float16)aR[3][j];                            \
        }                                                              \
        *(f16x8*)&As[buf][ar][((ac2) ^ (ar & 7)) * 8] = p0;            \
        *(f16x8*)&As[buf][ar][((ac2 + 1) ^ (ar & 7)) * 8] = p1;        \
        f16x8 q;                                                       \
        _Pragma("unroll") for (int j = 0; j < 8; ++j)                  \
            q[j] = (_Float16)bR[j];                                    \
        *(f16x8*)&Bs[buf][bn][(bc ^ (bn & 7)) * 8] = q;                \
    } while (0)

    const int KT = H_DIM / BK;   // 32, even
    LOAD1(aR0, bR0, 0);
    STORE1(0, aR0, bR0);
    LOAD1(aR0, bR0, BK);         // set0 now holds tile 1
    BAR();
    for (int kt = 0; kt < KT; kt += 2) {
        if (kt + 2 < KT) LOAD1(aR1, bR1, (kt + 2) * BK);
        G_COMPUTE(0);
        if (kt + 1 < KT) STORE1(1, aR0, bR0);
        BAR();
        if (kt + 3 < KT) LOAD1(aR0, bR0, (kt + 3) * BK);
        if (kt + 1 < KT) {
            G_COMPUTE(1);
            if (kt + 2 < KT) STORE1(0, aR1, bR1);
            BAR();
        }
    }
#undef LOAD1
#undef STORE1

    const int rows = cnt - m0;
#pragma unroll
    for (int i = 0; i < 2; ++i) {
#pragma unroll
        for (int rg = 0; rg < 4; ++rg) {
            int r = wm + i * 16 + kq * 4 + rg;
            if (r < rows) {
                int slot = base + m0 + r;
                float w = w_of_slot[slot];
                _Float16* hrow = hact + (size_t)slot * I_DIM + n0;
#pragma unroll
                for (int j = 0; j < 2; ++j) {
                    float v = acc[i][j][rg];
                    hrow[wn + j * 16 + rsel] = (_Float16)(v / (1.f + expf(-v)) * w);
                }
            }
        }
    }
}

// ---------------- GEMM2: out[tok, h] += hact[slot, :] . w2[e, :, h] ----------------
__global__ __launch_bounds__(NTHR, 4) void k_gemm2(
    const _Float16* __restrict__ hact, const float* __restrict__ W2,
    const int* __restrict__ counts, const int* __restrict__ bases,
    const int* __restrict__ tok_of_slot, float* __restrict__ out) {
    __shared__ _Float16 As[2][BM][BK];
    __shared__ _Float16 Bs[2][BN][BK];

    const int e = blockIdx.z;
    const int cnt = counts[e];
    const int m0 = blockIdx.y * BM;
    if (m0 >= cnt) return;
    const int base = bases[e];
    const int n0 = blockIdx.x * BN;
    const int tid = threadIdx.x;

    const int ar = tid >> 2;
    const int ac2 = (tid & 3) * 2;
    const int r_eff = min(ar, cnt - m0 - 1);
    const _Float16* arow = hact + (size_t)(base + m0 + r_eff) * I_DIM + (tid & 3) * 16;

    const int bn = tid & 63;
    const int bc = tid >> 6;
    const float* bcol = W2 + (size_t)e * (I_DIM * H_DIM) + (size_t)(bc * 8) * H_DIM + n0 + bn;

    const int wid = tid >> 6, lane = tid & 63;
    const int wm = (wid >> 1) * 32, wn = (wid & 1) * 32;
    const int rsel = lane & 15, kq = lane >> 4;

    f32x4 acc[2][2] = {};

    f16x8 aR0[2]; float bR0[8];
    f16x8 aR1[2]; float bR1[8];

#define LOAD2(aR, bR, k0)                                              \
    do {                                                               \
        aR[0] = *(const f16x8*)(arow + (k0));                          \
        aR[1] = *(const f16x8*)(arow + (k0) + 8);                      \
        const float* bp = bcol + (size_t)(k0) * H_DIM;                 \
        _Pragma("unroll") for (int j = 0; j < 8; ++j)                  \
            bR[j] = bp[(size_t)j * H_DIM];                             \
    } while (0)

#define STORE2(buf, aR, bR)                                            \
    do {                                                               \
        *(f16x8*)&As[buf][ar][((ac2) ^ (ar & 7)) * 8] = aR[0];         \
        *(f16x8*)&As[buf][ar][((ac2 + 1) ^ (ar & 7)) * 8] = aR[1];     \
        f16x8 q;                                                       \
        _Pragma("unroll") for (int j = 0; j < 8; ++j)                  \
            q[j] = (_Float16)bR[j];                                    \
        *(f16x8*)&Bs[buf][bn][(bc ^ (bn & 7)) * 8] = q;                \
    } while (0)

    const int KT = I_DIM / BK;   // 22, even
    LOAD2(aR0, bR0, 0);
    STORE2(0, aR0, bR0);
    LOAD2(aR0, bR0, BK);
    BAR();
    for (int kt = 0; kt < KT; kt += 2) {
        if (kt + 2 < KT) LOAD2(aR1, bR1, (kt + 2) * BK);
        G_COMPUTE(0);
        if (kt + 1 < KT) STORE2(1, aR0, bR0);
        BAR();
        if (kt + 3 < KT) LOAD2(aR0, bR0, (kt + 3) * BK);
        if (kt + 1 < KT) {
            G_COMPUTE(1);
            if (kt + 2 < KT) STORE2(0, aR1, bR1);
            BAR();
        }
    }
#undef LOAD2
#undef STORE2

    const int rows = cnt - m0;
#pragma unroll
    for (int i = 0; i < 2; ++i) {
#pragma unroll
        for (int rg = 0; rg < 4; ++rg) {
            int r = wm + i * 16 + kq * 4 + rg;
            if (r < rows) {
                int slot = base + m0 + r;
                int tok = tok_of_slot[slot];
                float* orow = out + (size_t)tok * H_DIM + n0;
#pragma unroll
                for (int j = 0; j < 2; ++j)
                    atomicAdd(&orow[wn + j * 16 + rsel], acc[i][j][rg]);
            }
        }
    }
}

extern "C" void kernel_launch(void* const* d_in, const int* in_sizes, int n_in,
                              void* d_out, int out_size, void* d_ws, size_t ws_size,
                              hipStream_t stream) {
    const float* X  = (const float*)d_in[0];
    const float* GW = (const float*)d_in[1];
    const float* W1 = (const float*)d_in[2];
    const float* W2 = (const float*)d_in[3];
    float* out = (float*)d_out;
    char* ws = (char*)d_ws;
    if (ws_size < (size_t)WS_NEEDED) return;

    int*   counts      = (int*)(ws + WS_COUNTS);
    int*   bases       = (int*)(ws + WS_BASES);
    int*   cursors     = (int*)(ws + WS_CURSORS);
    int*   topk_e      = (int*)(ws + WS_TOPK_E);
    float* topk_w      = (float*)(ws + WS_TOPK_W);
    int*   tok_of_slot = (int*)(ws + WS_TOK_OF_SLOT);
    float* w_of_slot   = (float*)(ws + WS_W_OF_SLOT);
    _Float16* hact     = (_Float16*)(ws + WS_HACT);

    hipMemsetAsync(counts, 0, N_EXP * sizeof(int), stream);
    hipMemsetAsync(out, 0, (size_t)T_TOK * H_DIM * sizeof(float), stream);
    k_router<<<T_TOK / 4, 256, 0, stream>>>(X, GW, counts, topk_e, topk_w);
    k_prefix<<<1, 64, 0, stream>>>(counts, bases, cursors);
    k_scatter<<<T_TOK / 256, 256, 0, stream>>>(topk_e, topk_w, bases, cursors,
                                               tok_of_slot, w_of_slot);
    // r3-proven 3D grids (n fastest, m middle, e slowest)
    k_gemm1<<<dim3(I_DIM / BN, T_TOK / BM, N_EXP), NTHR, 0, stream>>>(
        X, W1, counts, bases, tok_of_slot, w_of_slot, hact);
    k_gemm2<<<dim3(H_DIM / BN, T_TOK / BM, N_EXP), NTHR, 0, stream>>>(
        hact, W2, counts, bases, tok_of_slot, out);
}